// Round 10
// baseline (84.839 us; speedup 1.0000x reference)
//
#include <hip/hip_runtime.h>
#include <hip/hip_bf16.h>

// ---------------------------------------------------------------------------
// Diagonal-covariance GMM log-likelihoods as one bf16 MFMA GEMM + bias:
//   out[m,k] = sum_f [ x^2 * (-0.5/cov) + x * (mu/cov) ] + bias[k]
// GEMM: M=16384, N=512 (padded from 500), K2=2048 (interleaved x^2/x pairs)
//
// R9 = R8 minus A-in-LDS. R8 audit: LDS unit was ~52% busy (the top resource)
// while MFMA needed only ~8% — A staging (ds_write + ds_read + dbuf) was the
// load. A fragments are per-lane contiguous float4s of X, so each wave loads
// them DIRECTLY from global (coalesced 16 rows x 64B per instr; wave-pair
// duplicates hit L1) and packs (x^2,x)->bf16 in registers off the sync path.
//   - B: unchanged R8 tri-buffer, pre-swizzled image, global_load_lds DMA
//     two ahead, counted vmcnt(12) barriers (B(it+2) 4 + A(it+2) 8 in flight).
//   - A: 2 reg sets (aA/aB, unroll-2 static names); load issued after the
//     pack consumes the set (WAR-safe), two iterations ahead.
//   - LDS 48KB (3 B-buffers) + 32KB epilogue overlay.
// ---------------------------------------------------------------------------

typedef __attribute__((ext_vector_type(8))) __bf16 bf16x8;
typedef __attribute__((ext_vector_type(4))) float  f32x4;

#define LOG_2PI 1.837877066409345339082f

constexpr int M_TOT = 16384;   // B*T
constexpr int F_DIM = 1024;
constexpr int K_GMM = 500;
constexpr int N_PAD = 512;

constexpr int BM  = 128;
constexpr int BN  = 128;
constexpr int BKF = 32;              // K-step in floats (=> 64 bf16 along K2)
constexpr int NIT = F_DIM / BKF;     // 32 K-steps

// async global->LDS, 16B per lane (dest = uniform base + lane*16 in HW)
__device__ __forceinline__ void gload_lds16(const void* g, void* l) {
    __builtin_amdgcn_global_load_lds(
        (const __attribute__((address_space(1))) unsigned*)g,
        (__attribute__((address_space(3))) unsigned*)l, 16, 0, 0);
}

// pack (bf16(x*x), bf16(x)) into one dword: low16 = x^2 (even K2 slot), hi16 = x
__device__ __forceinline__ unsigned pack_sq_x(float x) {
    __hip_bfloat162 h = __float22bfloat162_rn(make_float2(x * x, x));
    union { __hip_bfloat162 h; unsigned u; } cv;
    cv.h = h;
    return cv.u;
}

// float4 -> one A fragment (8 bf16: (x0^2,x0),(x1^2,x1),...)
__device__ __forceinline__ bf16x8 pack_frag(float4 v) {
    union { uint4 u; bf16x8 h; } r;
    r.u.x = pack_sq_x(v.x);
    r.u.y = pack_sq_x(v.y);
    r.u.z = pack_sq_x(v.z);
    r.u.w = pack_sq_x(v.w);
    return r.h;
}

// ---------------------------------------------------------------------------
// prep: build the swizzled tiled W image + fp32 bias. (unchanged from R6/R8)
// Block (t,it) at dword offset (t*32+it)*4096 = LDS image for n_tile t,
// K-step it: row r (0..127), logical chunk cc stored at cc ^ (r&7).
// Element f -> it=f>>5, cc=(f>>2)&7, q=f&3: (bf16(-0.5/cov), bf16(mu/cov)).
// Rows k in [500,512) zeroed; bias=0 there.
// ---------------------------------------------------------------------------
__global__ __launch_bounds__(256) void prep_w_kernel(
    const float* __restrict__ mu, const float* __restrict__ cov,
    unsigned* __restrict__ Wimg, float* __restrict__ bias)
{
    const int k = blockIdx.x;           // 0..511 (component row)
    const int t = threadIdx.x;
    const int r  = k & 127;
    const int tt = k >> 7;
    const int rsw = r & 7;
    float sl = 0.f, sq = 0.f;
    #pragma unroll
    for (int j = 0; j < 4; ++j) {
        const int f  = t + j * 256;
        const int it = f >> 5;
        const int cc = (f >> 2) & 7;
        const int q  = f & 3;
        const int dw = (tt * 32 + it) * 4096 + r * 32 + ((cc ^ rsw) << 2) + q;
        if (k < K_GMM) {
            const float c = cov[k * F_DIM + f];
            const float m = mu[k * F_DIM + f];
            const float ic = 1.0f / c;
            __hip_bfloat162 h = __float22bfloat162_rn(make_float2(-0.5f * ic, m * ic));
            union { __hip_bfloat162 h; unsigned u; } cv; cv.h = h;
            Wimg[dw] = cv.u;
            sl += logf(c);
            sq += m * m * ic;
        } else {
            Wimg[dw] = 0u;
        }
    }
    #pragma unroll
    for (int off = 32; off > 0; off >>= 1) {
        sl += __shfl_down(sl, off, 64);
        sq += __shfl_down(sq, off, 64);
    }
    __shared__ float red[8];
    if ((t & 63) == 0) { red[(t >> 6) * 2] = sl; red[(t >> 6) * 2 + 1] = sq; }
    __syncthreads();
    if (t == 0) {
        const float SL = red[0] + red[2] + red[4] + red[6];
        const float SQ = red[1] + red[3] + red[5] + red[7];
        bias[k] = (k < K_GMM)
                ? (-0.5f * (F_DIM * LOG_2PI) - 0.5f * SL - 0.5f * SQ) : 0.f;
    }
}

// ---------------------------------------------------------------------------
// GEMM: 128x128 tile, 4 waves (2x2, each 64x64), mfma_f32_16x16x32_bf16.
// LDS 48KB = B tri-buffer (DMA'd pre-swizzled image); epilogue overlays 32KB.
// A fragments: direct per-lane float4 global loads + in-register pack.
// Counted-vmcnt barriers; 512 blocks (2/CU); n-siblings share XCD mod 8.
// ---------------------------------------------------------------------------
__global__ __launch_bounds__(256, 2) void gemm_kernel(
    const float* __restrict__ X, const unsigned* __restrict__ Wimg,
    const float* __restrict__ bias, float* __restrict__ out)
{
    __shared__ __align__(16) char smem[49152];
    float* ep = reinterpret_cast<float*>(smem);   // 64x128 fp32 epilogue (32KB)

    const int bid    = blockIdx.x;
    const int m_base = (bid & 127) * BM;
    const int n_tile = bid >> 7;
    const int n_base = n_tile * BN;

    const int tid  = threadIdx.x;
    const int lane = tid & 63;
    const int wv   = tid >> 6;
    const int wr   = (wv >> 1) * 64;    // wave row block (0/64)
    const int wc   = (wv & 1) * 64;     // wave col block (0/64)
    const int hi   = lane >> 4;         // 0..3
    const int lo   = lane & 15;
    const int lsw  = lo & 7;            // lane-constant fragment read swizzle

    const float4* Xv   = reinterpret_cast<const float4*>(X);   // X row = 256 float4
    const char*   Wimc = reinterpret_cast<const char*>(Wimg);

    // A-direct bases: fragment (a,c) of iter it = Xv[arow[a] + it*8 + c*4]
    int arow[4];
    #pragma unroll
    for (int a = 0; a < 4; ++a)
        arow[a] = (m_base + wr + a * 16 + lo) * (F_DIM / 4) + hi;

    f32x4 acc[4][4];
    #pragma unroll
    for (int a = 0; a < 4; ++a)
        #pragma unroll
        for (int b = 0; b < 4; ++b)
            acc[a][b] = (f32x4){0.f, 0.f, 0.f, 0.f};

    auto stageB = [&](int itS, int bufS) {            // 4 async DMA, 16KB total
        const char* gs = Wimc + (size_t)(n_tile * 32 + itS) * 16384;
        #pragma unroll
        for (int i = 0; i < 4; ++i)
            gload_lds16(gs + i * 4096 + wv * 1024 + lane * 16,
                        smem + bufS * 16384 + i * 4096 + wv * 1024);
    };
    auto loadA = [&](int itS, float4* ar) {           // 8 coalesced float4 loads
        #pragma unroll
        for (int a = 0; a < 4; ++a)
            #pragma unroll
            for (int c = 0; c < 2; ++c)
                ar[a * 2 + c] = Xv[arow[a] + itS * 8 + c * 4];
    };
    auto mfmas = [&](const bf16x8* pa, int bb) {      // 8 ds_read_b128 + 32 MFMA
        const unsigned short* Bsc =
            reinterpret_cast<const unsigned short*>(smem + bb * 16384);
        #pragma unroll
        for (int c = 0; c < 2; ++c) {
            bf16x8 bf[4];
            #pragma unroll
            for (int b = 0; b < 4; ++b) {
                const int row   = wc + b * 16 + lo;
                const int chunk = (c * 4 + hi) ^ lsw;
                bf[b] = *reinterpret_cast<const bf16x8*>(&Bsc[row * 64 + chunk * 8]);
            }
            #pragma unroll
            for (int a = 0; a < 4; ++a)
                #pragma unroll
                for (int b = 0; b < 4; ++b)
                    acc[a][b] = __builtin_amdgcn_mfma_f32_16x16x32_bf16(
                        pa[a * 2 + c], bf[b], acc[a][b], 0, 0, 0);
        }
    };

    // ---- prologue: A(0),A(1) to regs; B(0),B(1) DMA; counted barrier ----
    float4 aA[8], aB[8];
    loadA(0, aA);          // 8 vm (oldest)
    stageB(0, 0);          // 4 vm
    stageB(1, 1);          // 4 vm
    loadA(1, aB);          // 8 vm
    // retire A(0)+B(0) (oldest 12); leave B(1)+A(1)=12 in flight
    asm volatile("s_waitcnt vmcnt(12) lgkmcnt(0)" ::: "memory");
    __builtin_amdgcn_s_barrier();
    __builtin_amdgcn_sched_barrier(0);

    // ---- main loop: unroll-2, aA/aB ping-pong; B buffer = it%3 ----
    for (int it = 0; it < NIT; it += 2) {
        const int b0 = it % 3;
        const int b1 = (it + 1) % 3;
        const int b2 = (it + 2) % 3;
        const int b3 = (it + 3) % 3;

        // ===== iter it (even): consume aA, B buf b0 =====
        {
            if (it + 2 < NIT) stageB(it + 2, b2);
            bf16x8 pa[8];
            #pragma unroll
            for (int k = 0; k < 8; ++k) pa[k] = pack_frag(aA[k]);  // consume aA
            if (it + 2 < NIT) loadA(it + 2, aA);                   // WAR-safe refill
            mfmas(pa, b0);
            if (it + 2 < NIT)
                asm volatile("s_waitcnt vmcnt(12) lgkmcnt(0)" ::: "memory");
            else
                asm volatile("s_waitcnt vmcnt(0) lgkmcnt(0)" ::: "memory");
            __builtin_amdgcn_s_barrier();
            __builtin_amdgcn_sched_barrier(0);
        }

        // ===== iter it+1 (odd): consume aB, B buf b1 =====
        {
            if (it + 3 < NIT) stageB(it + 3, b3);
            bf16x8 pb[8];
            #pragma unroll
            for (int k = 0; k < 8; ++k) pb[k] = pack_frag(aB[k]);  // consume aB
            if (it + 3 < NIT) loadA(it + 3, aB);                   // WAR-safe refill
            mfmas(pb, b1);
            if (it + 3 < NIT)
                asm volatile("s_waitcnt vmcnt(12) lgkmcnt(0)" ::: "memory");
            else
                asm volatile("s_waitcnt vmcnt(0) lgkmcnt(0)" ::: "memory");
            __builtin_amdgcn_s_barrier();
            __builtin_amdgcn_sched_barrier(0);
        }
    }

    // ---- Epilogue: two 64-row passes; acc+bias -> LDS -> dense row writes ----
    // (final loop barrier + vmcnt(0)/lgkmcnt(0) separate last ds_reads from ep)
    const int ncols = (K_GMM - n_base < BN) ? (K_GMM - n_base) : BN;  // 128 or 116
    #pragma unroll
    for (int p = 0; p < 2; ++p) {
        if (p) __syncthreads();        // pass-0 reads done before pass-1 writes
        if ((wv >> 1) == p) {          // the 2 waves owning row-half p dump acc
            #pragma unroll
            for (int b = 0; b < 4; ++b) {
                const int col = wc + b * 16 + lo;
                const float bv = bias[n_base + col];
                #pragma unroll
                for (int a = 0; a < 4; ++a)
                    #pragma unroll
                    for (int i = 0; i < 4; ++i)
                        ep[(a * 16 + hi * 4 + i) * 128 + col] = acc[a][b][i] + bv;
            }
        }
        __syncthreads();
        #pragma unroll
        for (int k = 0; k < 8; ++k) {
            const int f    = k * 256 + tid;   // float4 id in 64x32 grid
            const int row  = f >> 5;
            const int slot = f & 31;
            if (slot * 4 < ncols) {
                const float4 v = *reinterpret_cast<const float4*>(&ep[row * 128 + slot * 4]);
                *reinterpret_cast<float4*>(
                    &out[(size_t)(m_base + p * 64 + row) * K_GMM + n_base + slot * 4]) = v;
            }
        }
    }
}

extern "C" void kernel_launch(void* const* d_in, const int* in_sizes, int n_in,
                              void* d_out, int out_size, void* d_ws, size_t ws_size,
                              hipStream_t stream)
{
    (void)in_sizes; (void)n_in; (void)out_size; (void)ws_size;
    const float* X   = (const float*)d_in[0];
    const float* mu  = (const float*)d_in[1];
    const float* cov = (const float*)d_in[2];
    float* out = (float*)d_out;

    // workspace: W image = 512*1024 dwords (2 MiB), then bias[512] f32
    unsigned* Wimg = (unsigned*)d_ws;
    float*    bias = (float*)((char*)d_ws + (size_t)N_PAD * F_DIM * 4);

    prep_w_kernel<<<dim3(N_PAD), dim3(256), 0, stream>>>(mu, cov, Wimg, bias);
    gemm_kernel<<<dim3((M_TOT / BM) * (N_PAD / BN)), dim3(256), 0, stream>>>(X, Wimg, bias, out);
}

// Round 11
// 56.106 us; speedup vs baseline: 1.5121x; 1.5121x over previous
//
#include <hip/hip_runtime.h>
#include <hip/hip_bf16.h>

// ---------------------------------------------------------------------------
// Diagonal-covariance GMM log-likelihoods as one bf16 MFMA GEMM + bias:
//   out[m,k] = sum_f [ x^2 * (-0.5/cov) + x * (mu/cov) ] + bias[k]
// GEMM: M=16384, N=512 (padded from 500), K2=2048 (interleaved x^2/x pairs)
//
// R10 = R8 with B moved from LDS to registers, coalescing fixed by layout:
//  - W image is FRAGMENT-MAJOR: per (n_tile, col-half, K-step, fragment) one
//    contiguous 1KB segment in exact lane order. A wave's B-fragment load is
//    one contiguous 1KB global_load_dwordx4 (R9's A-direct failed because X's
//    fixed layout forced 16 rows x 4KB stride = channel camping; W's layout
//    is ours to choose).
//  - B regs ping-pong (b0/b1), loaded ONE iter ahead, refilled after consume
//    (WAR-safe, auto-waitcnt via register deps). vmcnt NEVER drained in-loop.
//  - LDS = A double-buffer only (32KB); barrier = lgkmcnt(0) + s_barrier.
//    LDS unit work per block-iter halves vs R8 (was the top consumer ~45%).
//  - A-path identical to R8 (loads 2 ahead, pack 1 ahead, XOR-swizzled LDS).
//  - T5: s_setprio(1) around the MFMA cluster.
// ---------------------------------------------------------------------------

typedef __attribute__((ext_vector_type(8))) __bf16 bf16x8;
typedef __attribute__((ext_vector_type(4))) float  f32x4;

#define LOG_2PI 1.837877066409345339082f

constexpr int M_TOT = 16384;   // B*T
constexpr int F_DIM = 1024;
constexpr int K_GMM = 500;
constexpr int N_PAD = 512;

constexpr int BM  = 128;
constexpr int BN  = 128;
constexpr int BKF = 32;              // K-step in floats (=> 64 bf16 along K2)
constexpr int NIT = F_DIM / BKF;     // 32 K-steps

// pack (bf16(x*x), bf16(x)) into one dword: low16 = x^2 (even K2 slot), hi16 = x
__device__ __forceinline__ unsigned pack_sq_x(float x) {
    __hip_bfloat162 h = __float22bfloat162_rn(make_float2(x * x, x));
    union { __hip_bfloat162 h; unsigned u; } cv;
    cv.h = h;
    return cv.u;
}

// ---------------------------------------------------------------------------
// prep: build the FRAGMENT-MAJOR W image + fp32 bias.
// Row k (0..511): tt=k>>7 (n_tile), wch=(k>>6)&1 (col-half), b=(k>>4)&3, lo=k&15.
// Row dword d (0..1023): it=d>>5, c=(d>>4)&1, hi=(d>>2)&3, jj=d&3.
// Image dword addr = (((tt*2+wch)*32+it)*8 + (b*2+c))*256 + (hi*16+lo)*4 + jj.
// => per (tt,wch,it,frag) a contiguous 1KB block in exact lane order.
// Value: (bf16(-0.5/cov), bf16(mu/cov)); rows k>=500 zeroed, bias=0 there.
// ---------------------------------------------------------------------------
__global__ __launch_bounds__(256) void prep_w_kernel(
    const float* __restrict__ mu, const float* __restrict__ cov,
    unsigned* __restrict__ Wimg, float* __restrict__ bias)
{
    const int k = blockIdx.x;           // 0..511 (component row)
    const int t = threadIdx.x;
    const int tt  = k >> 7;
    const int wch = (k >> 6) & 1;
    const int b   = (k >> 4) & 3;
    const int lo  = k & 15;
    float sl = 0.f, sq = 0.f;
    #pragma unroll
    for (int j = 0; j < 4; ++j) {
        const int d  = t + j * 256;          // row dword index 0..1023
        const int it = d >> 5;
        const int c  = (d >> 4) & 1;
        const int hi = (d >> 2) & 3;
        const int jj = d & 3;
        const int dw = ((((tt * 2 + wch) * 32 + it) * 8) + (b * 2 + c)) * 256
                     + (hi * 16 + lo) * 4 + jj;
        if (k < K_GMM) {
            const float cv_ = cov[k * F_DIM + d];
            const float m_  = mu[k * F_DIM + d];
            const float ic  = 1.0f / cv_;
            __hip_bfloat162 h = __float22bfloat162_rn(make_float2(-0.5f * ic, m_ * ic));
            union { __hip_bfloat162 h; unsigned u; } cvt; cvt.h = h;
            Wimg[dw] = cvt.u;
            sl += logf(cv_);
            sq += m_ * m_ * ic;
        } else {
            Wimg[dw] = 0u;
        }
    }
    #pragma unroll
    for (int off = 32; off > 0; off >>= 1) {
        sl += __shfl_down(sl, off, 64);
        sq += __shfl_down(sq, off, 64);
    }
    __shared__ float red[8];
    if ((t & 63) == 0) { red[(t >> 6) * 2] = sl; red[(t >> 6) * 2 + 1] = sq; }
    __syncthreads();
    if (t == 0) {
        const float SL = red[0] + red[2] + red[4] + red[6];
        const float SQ = red[1] + red[3] + red[5] + red[7];
        bias[k] = (k < K_GMM)
                ? (-0.5f * (F_DIM * LOG_2PI) - 0.5f * SL - 0.5f * SQ) : 0.f;
    }
}

// ---------------------------------------------------------------------------
// GEMM: 128x128 tile, 4 waves (2x2, each 64x64), mfma_f32_16x16x32_bf16.
// LDS 32KB = A double-buffer (XOR-swizzled [128][64] bf16); epilogue overlay.
// B: per-wave contiguous 1KB fragment loads from the fragment-major image,
// ping-pong reg sets one iter ahead. Barriers are lgkmcnt-only.
// 512 blocks (2/CU); n-siblings of an m-tile are 128 apart in bid (same XCD).
// ---------------------------------------------------------------------------
__global__ __launch_bounds__(256, 2) void gemm_kernel(
    const float* __restrict__ X, const unsigned* __restrict__ Wimg,
    const float* __restrict__ bias, float* __restrict__ out)
{
    __shared__ __align__(16) char smem[32768];
    float* ep = reinterpret_cast<float*>(smem);   // 64x128 fp32 epilogue (32KB)

    const int bid    = blockIdx.x;
    const int m_base = (bid & 127) * BM;
    const int n_tile = bid >> 7;
    const int n_base = n_tile * BN;

    const int tid  = threadIdx.x;
    const int lane = tid & 63;
    const int wv   = tid >> 6;
    const int wr   = (wv >> 1) * 64;    // wave row block (0/64)
    const int wch  = wv & 1;            // wave col-half
    const int wc   = wch * 64;
    const int hi   = lane >> 4;         // 0..3
    const int lo   = lane & 15;
    const int lsw  = lo & 7;            // lane-constant fragment read swizzle

    const int sr = tid >> 1;            // A staging row 0..127
    const int sh = tid & 1;             // staging half (chunks 0-3 / 4-7)

    const float4* Xv = reinterpret_cast<const float4*>(X);     // X row = 256 float4
    const bf16x8* Wf = reinterpret_cast<const bf16x8*>(Wimg);
    // wave's image base, in bf16x8 units: (n_tile*2+wch) * 32 steps * 8 frags * 64 lanes
    const int wbase = (n_tile * 2 + wch) * 32 * 8 * 64;

    f32x4 acc[4][4];
    #pragma unroll
    for (int a = 0; a < 4; ++a)
        #pragma unroll
        for (int b = 0; b < 4; ++b)
            acc[a][b] = (f32x4){0.f, 0.f, 0.f, 0.f};

    auto loadA = [&](int itS, float4* ar) {           // 4 global float4 (staging)
        #pragma unroll
        for (int j = 0; j < 4; ++j)
            ar[j] = Xv[(m_base + sr) * (F_DIM / 4) + itS * 8 + sh * 4 + j];
    };
    auto packA = [&](const float4* ar, int ab) {      // pack + swizzled ds_write
        unsigned short* Ad = reinterpret_cast<unsigned short*>(smem + ab * 16384);
        #pragma unroll
        for (int j = 0; j < 4; ++j) {
            const int chunk = (sh * 4 + j) ^ (sr & 7);
            uint4 wa;
            wa.x = pack_sq_x(ar[j].x);
            wa.y = pack_sq_x(ar[j].y);
            wa.z = pack_sq_x(ar[j].z);
            wa.w = pack_sq_x(ar[j].w);
            *reinterpret_cast<uint4*>(&Ad[sr * 64 + chunk * 8]) = wa;
        }
    };
    auto loadB = [&](int itS, bf16x8* br) {           // 8 contiguous 1KB wave-loads
        #pragma unroll
        for (int f = 0; f < 8; ++f)
            br[f] = Wf[wbase + (itS * 8 + f) * 64 + lane];
    };
    auto mfmas = [&](int ab, const bf16x8* br) {      // 8 ds_read_b128 + 32 MFMA
        const unsigned short* Asc =
            reinterpret_cast<const unsigned short*>(smem + ab * 16384);
        bf16x8 af[4];
        __builtin_amdgcn_s_setprio(1);
        #pragma unroll
        for (int c = 0; c < 2; ++c) {
            #pragma unroll
            for (int a = 0; a < 4; ++a) {
                const int row   = wr + a * 16 + lo;
                const int chunk = (c * 4 + hi) ^ lsw;
                af[a] = *reinterpret_cast<const bf16x8*>(&Asc[row * 64 + chunk * 8]);
            }
            #pragma unroll
            for (int a = 0; a < 4; ++a)
                #pragma unroll
                for (int b = 0; b < 4; ++b)
                    acc[a][b] = __builtin_amdgcn_mfma_f32_16x16x32_bf16(
                        af[a], br[b * 2 + c], acc[a][b], 0, 0, 0);
        }
        __builtin_amdgcn_s_setprio(0);
    };

    // ---- prologue ----
    float4 aA[4], aB[4];
    bf16x8 b0[8], b1[8];
    loadA(0, aA);
    loadB(0, b0);
    loadA(1, aB);
    loadB(1, b1);
    packA(aA, 0);          // auto-waits aA's loads only
    loadA(2, aA);
    asm volatile("s_waitcnt lgkmcnt(0)" ::: "memory");
    __builtin_amdgcn_s_barrier();
    __builtin_amdgcn_sched_barrier(0);

    // ---- main loop: unroll-2; A bufs ping-pong, B reg sets ping-pong ----
    for (int it = 0; it < NIT; it += 2) {
        // ===== even iter it: compute Abuf0 x b0 =====
        packA(aB, 1);                         // A(it+1) -> Abuf1 (always valid)
        if (it + 3 < NIT) loadA(it + 3, aB);  // refill after consume
        mfmas(0, b0);
        if (it + 2 < NIT) loadB(it + 2, b0);  // refill after consume
        asm volatile("s_waitcnt lgkmcnt(0)" ::: "memory");
        __builtin_amdgcn_s_barrier();
        __builtin_amdgcn_sched_barrier(0);

        // ===== odd iter it+1: compute Abuf1 x b1 =====
        if (it + 2 < NIT) packA(aA, 0);       // A(it+2) -> Abuf0
        if (it + 4 < NIT) loadA(it + 4, aA);
        mfmas(1, b1);
        if (it + 3 < NIT) loadB(it + 3, b1);
        asm volatile("s_waitcnt lgkmcnt(0)" ::: "memory");
        __builtin_amdgcn_s_barrier();
        __builtin_amdgcn_sched_barrier(0);
    }

    // ---- Epilogue: two 64-row passes; acc+bias -> LDS -> dense row writes ----
    // (final loop barrier separates last ds_reads from ep reuse)
    const int ncols = (K_GMM - n_base < BN) ? (K_GMM - n_base) : BN;  // 128 or 116
    #pragma unroll
    for (int p = 0; p < 2; ++p) {
        if (p) __syncthreads();        // pass-0 reads done before pass-1 writes
        if ((wv >> 1) == p) {          // the 2 waves owning row-half p dump acc
            #pragma unroll
            for (int b = 0; b < 4; ++b) {
                const int col = wc + b * 16 + lo;
                const float bv = bias[n_base + col];
                #pragma unroll
                for (int a = 0; a < 4; ++a)
                    #pragma unroll
                    for (int i = 0; i < 4; ++i)
                        ep[(a * 16 + hi * 4 + i) * 128 + col] = acc[a][b][i] + bv;
            }
        }
        __syncthreads();
        #pragma unroll
        for (int k = 0; k < 8; ++k) {
            const int f    = k * 256 + tid;   // float4 id in 64x32 grid
            const int row  = f >> 5;
            const int slot = f & 31;
            if (slot * 4 < ncols) {
                const float4 v = *reinterpret_cast<const float4*>(&ep[row * 128 + slot * 4]);
                *reinterpret_cast<float4*>(
                    &out[(size_t)(m_base + p * 64 + row) * K_GMM + n_base + slot * 4]) = v;
            }
        }
    }
}

extern "C" void kernel_launch(void* const* d_in, const int* in_sizes, int n_in,
                              void* d_out, int out_size, void* d_ws, size_t ws_size,
                              hipStream_t stream)
{
    (void)in_sizes; (void)n_in; (void)out_size; (void)ws_size;
    const float* X   = (const float*)d_in[0];
    const float* mu  = (const float*)d_in[1];
    const float* cov = (const float*)d_in[2];
    float* out = (float*)d_out;

    // workspace: W image = 512*1024 dwords (2 MiB), then bias[512] f32
    unsigned* Wimg = (unsigned*)d_ws;
    float*    bias = (float*)((char*)d_ws + (size_t)N_PAD * F_DIM * 4);

    prep_w_kernel<<<dim3(N_PAD), dim3(256), 0, stream>>>(mu, cov, Wimg, bias);
    gemm_kernel<<<dim3((M_TOT / BM) * (N_PAD / BN)), dim3(256), 0, stream>>>(X, Wimg, bias, out);
}